// Round 10
// baseline (448.569 us; speedup 1.0000x reference)
//
#include <hip/hip_runtime.h>
#include <math.h>

#define BN 4
#define SN 1024
#define EN 512
#define HN 8
#define LN 4
#define DN 64
#define OBSN 128
#define NR (BN*SN)            // 4096 rows
#define NB (NR*EN)            // elements per activation buffer
#define EPSF 1e-6f

typedef __attribute__((ext_vector_type(8))) short short8v;
typedef __attribute__((ext_vector_type(4))) float f32x4;
typedef unsigned short u16;

__device__ __forceinline__ float logk_of(int h){
    const float start = -3.4657359027997265f;   // log(1/32)
    const float step  = -0.3960841031771117f;   // (log(1/512)-log(1/32))/7
    return logf(1.0f - expf(start + step*(float)h));
}
__device__ __forceinline__ float geluf(float x){
    float x3 = x*x*x;
    return 0.5f*x*(1.0f + tanhf(0.7978845608028654f*(x + 0.044715f*x3)));
}
__device__ __forceinline__ float siluf(float x){
    return x / (1.0f + expf(-x));
}
__device__ __forceinline__ u16 f2bf(float x){
    union { float f; unsigned u; } v; v.f = x;
    unsigned r = v.u + 0x7FFFu + ((v.u >> 16) & 1u);
    return (u16)(r >> 16);
}
__device__ __forceinline__ float bf2f(u16 x){
    union { unsigned u; float f; } v; v.u = ((unsigned)x)<<16;
    return v.f;
}
__device__ __forceinline__ void load_lds16(const void* g, void* l){
    __builtin_amdgcn_global_load_lds((const __attribute__((address_space(1))) void*)g,
                                     (__attribute__((address_space(3))) void*)l, 16, 0, 0);
}
// XOR swizzle for 64-row x 128B LDS tiles
__device__ __forceinline__ int swz(int r, int bo){ return r*128 + (bo ^ ((r&7)<<4)); }

// ---------------- segment cumsum (inclusive) ----------------
__global__ void seg_kernel(const int* __restrict__ dones, int* __restrict__ seg){
    __shared__ int sm[SN];
    int b = blockIdx.x, t = threadIdx.x;
    sm[t] = dones[b*SN + t];
    __syncthreads();
    for (int off=1; off<SN; off<<=1){
        int v = (t>=off) ? sm[t-off] : 0;
        __syncthreads();
        sm[t] += v;
        __syncthreads();
    }
    seg[b*SN + t] = sm[t];
}

// ---------------- weight convert+transpose: f32 [K][M] -> bf16 [M][K] ----------------
__global__ void wconv8_kernel(const float* w0, const float* w1, const float* w2,
                              const float* w3, const float* w4, const float* w5,
                              const float* w6, const float* w7,
                              u16* __restrict__ dst){
    __shared__ u16 tile[32][33];
    int z = blockIdx.z;
    int type = z>>2, layer = z&3;
    const float* srcs[8] = {w0,w1,w2,w3,w4,w5,w6,w7};
    const float* s = srcs[type] + (size_t)layer*EN*EN;
    u16* d = dst + ((size_t)type*LN + layer)*EN*EN;
    int k0 = blockIdx.y*32, m0 = blockIdx.x*32;
    int tx = threadIdx.x, ty = threadIdx.y;   // 32, 8
    #pragma unroll
    for (int i=0;i<32;i+=8)
        tile[tx][ty+i] = f2bf(s[(size_t)(k0+ty+i)*EN + m0+tx]);
    __syncthreads();
    #pragma unroll
    for (int i=0;i<32;i+=8)
        d[(size_t)(m0+ty+i)*EN + k0+tx] = tile[ty+i][tx];
}
__global__ void wconv_kernel(const float* __restrict__ src, u16* __restrict__ dst,
                             int K, int M){
    __shared__ u16 tile[32][33];
    int k0 = blockIdx.y*32, m0 = blockIdx.x*32;
    int tx = threadIdx.x, ty = threadIdx.y;
    #pragma unroll
    for (int i=0;i<32;i+=8)
        tile[tx][ty+i] = f2bf(src[(size_t)(k0+ty+i)*M + m0+tx]);
    __syncthreads();
    #pragma unroll
    for (int i=0;i<32;i+=8)
        dst[(size_t)(m0+ty+i)*K + k0+tx] = tile[ty+i][tx];
}

// ---------------- rmsnorm (one wave per row), optional f32 + bf16 outputs ----------------
template<int COLS, bool WF32, bool WBF>
__global__ void rmsnorm_kernel(const float* __restrict__ A,
                               const float* __restrict__ scale,
                               float* __restrict__ Of,
                               u16* __restrict__ Ob){
    constexpr int PER = COLS/64;
    int row  = blockIdx.x*4 + (threadIdx.x>>6);
    int lane = threadIdx.x & 63;
    const float* a = A + (size_t)row*COLS;
    float v[PER];
    float ss = 0.f;
    #pragma unroll
    for (int i=0;i<PER;i++){
        float x = a[lane + i*64];
        v[i] = x; ss += x*x;
    }
    #pragma unroll
    for (int off=32; off>0; off>>=1) ss += __shfl_xor(ss, off, 64);
    float rs = rsqrtf(ss*(1.0f/COLS) + EPSF);
    #pragma unroll
    for (int i=0;i<PER;i++){
        float o = v[i]*rs*scale[lane + i*64];
        if (WF32) Of[(size_t)row*COLS + lane + i*64] = o;
        if (WBF)  Ob[(size_t)row*COLS + lane + i*64] = f2bf(o);
    }
}

// ======== MFMA tile helpers — BM=128, BN=64, BK=64; 512 threads = 8 waves (4x2) ========
// A tile: 128 rows x 64 k (16 KB), staged 2x16B per thread
__device__ __forceinline__ void stage_tileA(const u16* __restrict__ G, size_t rowBase,
                                            int K, int k0, u16* dst, int t){
    #pragma unroll
    for (int i=0;i<2;i++){
        int o = i*8192 + t*16;
        int grow = o>>7, gcolb = o&127;
        load_lds16(G + (rowBase+grow)*K + k0 + (gcolb>>1), (char*)dst + o);
    }
}
// B tile: 64 rows x 64 k (8 KB), staged 1x16B per thread
__device__ __forceinline__ void stage_tileB(const u16* __restrict__ G, size_t rowBase,
                                            int K, int k0, u16* dst, int t){
    int o = t*16;
    int grow = o>>7, gcolb = o&127;
    load_lds16(G + (rowBase+grow)*K + k0 + (gcolb>>1), (char*)dst + o);
}
__device__ __forceinline__ void mma_tile(const u16* As, const u16* Bs, f32x4 acc[2][2],
                                         int wr, int wc, int lane){
    #pragma unroll
    for (int kk=0; kk<64; kk+=32){
        int kb = kk + (lane>>4)*8;
        short8v a[2], b[2];
        #pragma unroll
        for (int m=0;m<2;m++)
            a[m] = *(const short8v*)((const char*)As + (wr*32+m*16+(lane&15))*128 + kb*2);
        #pragma unroll
        for (int n=0;n<2;n++)
            b[n] = *(const short8v*)((const char*)Bs + (wc*32+n*16+(lane&15))*128 + kb*2);
        #pragma unroll
        for (int m=0;m<2;m++)
            #pragma unroll
            for (int n=0;n<2;n++)
                acc[m][n] = __builtin_amdgcn_mfma_f32_16x16x32_bf16(a[m], b[n], acc[m][n], 0,0,0);
    }
}
#define ZERO_ACC(acc) { _Pragma("unroll") for (int m=0;m<2;m++) _Pragma("unroll") for (int n=0;n<2;n++){ acc[m][n][0]=0.f;acc[m][n][1]=0.f;acc[m][n][2]=0.f;acc[m][n][3]=0.f; } }

// ---------------- fused QKVG GEMM (BM=128, 2-phase, decay-prescaled Q/K epilogue) ----------------
__global__ __launch_bounds__(512) void gemm_qkvg(
    const u16* __restrict__ A,
    const u16* __restrict__ WQ, const u16* __restrict__ WK,
    const u16* __restrict__ WV, const u16* __restrict__ WG,
    const int* __restrict__ tsid,
    u16* __restrict__ Qbb, u16* __restrict__ Kbb,
    u16* __restrict__ VtT, u16* __restrict__ KtT, u16* __restrict__ Gb)
{
    __shared__ u16 As[2][128*64];
    __shared__ u16 Bs[2][4][64*64];
    int t = threadIdx.x;
    int row0 = blockIdx.y*128, col0 = blockIdx.x*64;
    int w = t>>6, lane = t&63;
    int wr = w>>1, wc = w&1;     // 4 x 2 waves
    f32x4 accQ[2][2], accK[2][2], accV[2][2], accG[2][2];
    ZERO_ACC(accQ); ZERO_ACC(accK); ZERO_ACC(accV); ZERO_ACC(accG);
    const u16* Ws[4] = {WQ, WK, WV, WG};

    stage_tileA(A, (size_t)row0, EN, 0, As[0], t);
    #pragma unroll
    for (int wt=0; wt<4; wt++) stage_tileB(Ws[wt], (size_t)col0, EN, 0, Bs[0][wt], t);
    __syncthreads();
    for (int ti=0; ti<EN/64; ++ti){
        int cur = ti&1;
        if (ti+1 < EN/64){
            stage_tileA(A, (size_t)row0, EN, (ti+1)*64, As[cur^1], t);
            #pragma unroll
            for (int wt=0; wt<4; wt++)
                stage_tileB(Ws[wt], (size_t)col0, EN, (ti+1)*64, Bs[cur^1][wt], t);
        }
        mma_tile(As[cur], Bs[cur][0], accQ, wr, wc, lane);
        mma_tile(As[cur], Bs[cur][1], accK, wr, wc, lane);
        mma_tile(As[cur], Bs[cur][2], accV, wr, wc, lane);
        mma_tile(As[cur], Bs[cur][3], accG, wr, wc, lane);
        __syncthreads();
    }
    // decay pre-scale: col tile == head (grid.x = 8)
    float lk = logk_of(blockIdx.x);
    float eqv[2][4], emv[2][4];
    #pragma unroll
    for (int m=0;m<2;m++)
        #pragma unroll
        for (int j=0;j<4;j++){
            int row = row0 + wr*32 + m*16 + (lane>>4)*4 + j;
            float tq = (float)tsid[row];
            eqv[m][j] = expf(tq*lk);
            emv[m][j] = expf(-tq*lk);
        }
    #pragma unroll
    for (int m=0;m<2;m++){
        #pragma unroll
        for (int n=0;n<2;n++){
            int col = col0 + wc*32 + n*16 + (lane&15);
            int rbase = row0 + wr*32 + m*16 + (lane>>4)*4;
            ushort4 pkV, pkK;
            #pragma unroll
            for (int j=0;j<4;j++){
                size_t idx = (size_t)(rbase+j)*EN + col;
                Qbb[idx] = f2bf(eqv[m][j]*accQ[m][n][j]);
                float kx = emv[m][j]*0.125f*accK[m][n][j];
                Kbb[idx] = f2bf(kx);
                ((u16*)&pkK)[j] = f2bf(kx);
                ((u16*)&pkV)[j] = f2bf(accV[m][n][j]);
                Gb[idx] = f2bf(siluf(accG[m][n][j]));
            }
            int bb = rbase>>10;
            int s0 = rbase&1023;
            *(ushort4*)(VtT + ((size_t)bb*EN + col)*SN + s0) = pkV;
            *(ushort4*)(KtT + ((size_t)bb*EN + col)*SN + s0) = pkK;
        }
    }
}

// ---------------- fused swiglu pair (BM=128, 2-phase) ----------------
__global__ __launch_bounds__(512) void gemm_swpair(
    const u16* __restrict__ A,
    const u16* __restrict__ WGt, const u16* __restrict__ WLt,
    u16* __restrict__ Out)
{
    __shared__ u16 As[2][128*64];
    __shared__ u16 Bg[2][64*64];
    __shared__ u16 Bl[2][64*64];
    int t = threadIdx.x;
    int row0 = blockIdx.y*128, col0 = blockIdx.x*64;
    int w = t>>6, lane = t&63;
    int wr = w>>1, wc = w&1;
    f32x4 accG[2][2], accL[2][2];
    ZERO_ACC(accG); ZERO_ACC(accL);
    stage_tileA(A, (size_t)row0, EN, 0, As[0], t);
    stage_tileB(WGt, (size_t)col0, EN, 0, Bg[0], t);
    stage_tileB(WLt, (size_t)col0, EN, 0, Bl[0], t);
    __syncthreads();
    for (int ti=0; ti<EN/64; ++ti){
        int cur = ti&1;
        if (ti+1 < EN/64){
            stage_tileA(A, (size_t)row0, EN, (ti+1)*64, As[cur^1], t);
            stage_tileB(WGt, (size_t)col0, EN, (ti+1)*64, Bg[cur^1], t);
            stage_tileB(WLt, (size_t)col0, EN, (ti+1)*64, Bl[cur^1], t);
        }
        mma_tile(As[cur], Bg[cur], accG, wr, wc, lane);
        mma_tile(As[cur], Bl[cur], accL, wr, wc, lane);
        __syncthreads();
    }
    #pragma unroll
    for (int m=0;m<2;m++){
        #pragma unroll
        for (int n=0;n<2;n++){
            int col = col0 + wc*32 + n*16 + (lane&15);
            int rbase = row0 + wr*32 + m*16 + (lane>>4)*4;
            #pragma unroll
            for (int j=0;j<4;j++){
                float x = siluf(accG[m][n][j]) * accL[m][n][j];
                Out[(size_t)(rbase+j)*EN + col] = f2bf(x);
            }
        }
    }
}

// ---------------- plain bf16 GEMM (BM=128, 2-phase; residual read as bf16) ----------------
template<int ACT, bool BIASF, bool RESF, int OUTM>
__global__ __launch_bounds__(512) void gemm_bf16(
    const u16* __restrict__ A, const u16* __restrict__ Wt,
    const float* __restrict__ bias, const u16* __restrict__ res,
    float* __restrict__ C, u16* __restrict__ Ob, int K, float scale)
{
    __shared__ u16 As[2][128*64];
    __shared__ u16 Bs[2][64*64];
    int t = threadIdx.x;
    int row0 = blockIdx.y*128, col0 = blockIdx.x*64;
    int w = t>>6, lane = t&63;
    int wr = w>>1, wc = w&1;
    f32x4 acc[2][2];
    ZERO_ACC(acc);
    int nt = K/64;
    stage_tileA(A, (size_t)row0, K, 0, As[0], t);
    stage_tileB(Wt, (size_t)col0, K, 0, Bs[0], t);
    __syncthreads();
    for (int ti=0; ti<nt; ++ti){
        int cur = ti&1;
        if (ti+1 < nt){
            stage_tileA(A, (size_t)row0, K, (ti+1)*64, As[cur^1], t);
            stage_tileB(Wt, (size_t)col0, K, (ti+1)*64, Bs[cur^1], t);
        }
        mma_tile(As[cur], Bs[cur], acc, wr, wc, lane);
        __syncthreads();
    }
    #pragma unroll
    for (int m=0;m<2;m++){
        #pragma unroll
        for (int n=0;n<2;n++){
            int col = col0 + wc*32 + n*16 + (lane&15);
            int rbase = row0 + wr*32 + m*16 + (lane>>4)*4;
            #pragma unroll
            for (int j=0;j<4;j++){
                float x = acc[m][n][j]*scale;
                if (BIASF) x += bias[col];
                if (ACT==1) x = siluf(x);
                if (ACT==2) x = geluf(x);
                if (RESF) x += bf2f(res[(size_t)(rbase+j)*512 + col]);
                if (OUTM&1) C[(size_t)(rbase+j)*512 + col] = x;
                if (OUTM&2) Ob[(size_t)(rbase+j)*512 + col] = f2bf(x);
            }
        }
    }
}

// ---------------- MFMA retention (decay-prescaled) + groupnorm + gate-mul + fused h_new ----------------
// grid (17, B*H): blockIdx.x==0 -> h_new role; else q-tile = 16-blockIdx.x (heavy first).
__global__ __launch_bounds__(256) void retention_mfma(
    const u16* __restrict__ Qbb, const u16* __restrict__ Kbb,
    const u16* __restrict__ VtT, const u16* __restrict__ KtT,
    const float* __restrict__ hstate, const int* __restrict__ tsid, const int* __restrict__ seg,
    const float* __restrict__ gns, const float* __restrict__ gnb,
    const u16* __restrict__ Gb, u16* __restrict__ Out,
    float* __restrict__ Hout, int layer)
{
    int bh = blockIdx.y; int b = bh>>3; int h = bh&7;
    int t = threadIdx.x, lane = t&63, w = t>>6;
    __shared__ u16 Qs[64*64];
    __shared__ u16 Ks[64*64];
    __shared__ u16 Vts[64*64];
    __shared__ u16 Ps[64*64];
    __shared__ float tsq_s[64];
    __shared__ int   segq_s[64];
    __shared__ float tsm_s[64];
    __shared__ int   segm_s[64];
    float lk = logk_of(h);

    if (blockIdx.x == 0){
        // ---- h_new role: ho = h0*hd + cfac * sum_m (K'[m] & mask) (x) V[m] ----
        float tmax = (float)tsid[b*SN + SN-1];
        int segl = seg[b*SN + SN-1];
        u16* m16 = Qs;          // 1024-entry 0xFFFF/0 mask in Qs region
        #pragma unroll
        for (int i=0;i<4;i++){
            int m = t + i*256;
            m16[m] = (seg[b*SN+m]==segl) ? (u16)0xFFFFu : (u16)0;
        }
        f32x4 eacc[4];
        #pragma unroll
        for (int en=0;en<4;en++){ eacc[en][0]=0.f; eacc[en][1]=0.f; eacc[en][2]=0.f; eacc[en][3]=0.f; }
        for (int mt=0; mt<16; ++mt){
            int m0 = mt*64;
            __syncthreads();
            #pragma unroll
            for (int i=0;i<2;i++){
                int c = t + i*256; int r = c>>3, cb = (c&7)*16;
                int mb = m0 + (cb>>1);
                size_t g = ((size_t)(b*EN) + h*DN + r)*SN + mb;
                short8v kt = *(const short8v*)(KtT + g);
                short8v vt = *(const short8v*)(VtT + g);
                short8v mv = *(const short8v*)(m16 + mb);
                kt &= mv;
                *(short8v*)((char*)Ks  + swz(r,cb)) = kt;
                *(short8v*)((char*)Vts + swz(r,cb)) = vt;
            }
            __syncthreads();
            short8v a0 = *(short8v*)((char*)Ks + swz(w*16+(lane&15), (lane>>4)*16));
            short8v a1 = *(short8v*)((char*)Ks + swz(w*16+(lane&15), 64+(lane>>4)*16));
            __builtin_amdgcn_s_setprio(1);
            #pragma unroll
            for (int en=0;en<4;en++){
                short8v b0 = *(short8v*)((char*)Vts + swz(en*16+(lane&15), (lane>>4)*16));
                short8v b1 = *(short8v*)((char*)Vts + swz(en*16+(lane&15), 64+(lane>>4)*16));
                eacc[en] = __builtin_amdgcn_mfma_f32_16x16x32_bf16(a0, b0, eacc[en], 0,0,0);
                eacc[en] = __builtin_amdgcn_mfma_f32_16x16x32_bf16(a1, b1, eacc[en], 0,0,0);
            }
            __builtin_amdgcn_s_setprio(0);
        }
        float cfac = expf(tmax*lk);
        float hd = (segl==0) ? expf((tmax+1.0f)*lk) : 0.f;
        const float* h0 = hstate + ((size_t)bh*LN + layer)*4096;
        float* ho = Hout + ((size_t)bh*LN + layer)*4096;
        #pragma unroll
        for (int en=0;en<4;en++){
            int e = en*16 + (lane&15);
            #pragma unroll
            for (int j=0;j<4;j++){
                int d = w*16 + (lane>>4)*4 + j;
                ho[d*64 + e] = h0[d*64 + e]*hd + cfac*eacc[en][j];
            }
        }
        return;
    }

    // ---- retention role ----
    int tile = 16 - (int)blockIdx.x;   // 15..0, heavy first
    int n0 = tile*64;

    #pragma unroll
    for (int i=0;i<2;i++){
        int c = t + i*256; int r = c>>3, cb = (c&7)*16;
        short8v qv = *(const short8v*)(Qbb + (size_t)(b*SN + n0 + r)*EN + h*DN + (cb>>1));
        *(short8v*)((char*)Qs + swz(r,cb)) = qv;
    }
    const float* h0 = hstate + ((size_t)bh*LN + layer)*4096;
    #pragma unroll
    for (int i=0;i<4;i++){
        int idx = t + i*256; int d = idx>>4, e0 = (idx&15)*4;
        float4 hv = *(const float4*)(h0 + d*64 + e0);
        *(u16*)((char*)Ps + swz(e0+0, 2*d)) = f2bf(hv.x);
        *(u16*)((char*)Ps + swz(e0+1, 2*d)) = f2bf(hv.y);
        *(u16*)((char*)Ps + swz(e0+2, 2*d)) = f2bf(hv.z);
        *(u16*)((char*)Ps + swz(e0+3, 2*d)) = f2bf(hv.w);
    }
    if (t<64){
        tsq_s[t] = (float)tsid[b*SN+n0+t];
        segq_s[t] = seg[b*SN+n0+t];
    }
    // prefetch m-tile 0 K/V into registers
    short8v kr0, kr1, vr0, vr1;
    {
        int c0 = t, c1 = t+256;
        int r0=c0>>3, cb0=(c0&7)*16, r1=c1>>3, cb1=(c1&7)*16;
        kr0 = *(const short8v*)(Kbb + (size_t)(b*SN+r0)*EN + h*DN + (cb0>>1));
        kr1 = *(const short8v*)(Kbb + (size_t)(b*SN+r1)*EN + h*DN + (cb1>>1));
        vr0 = *(const short8v*)(VtT + ((size_t)(b*EN)+h*DN+r0)*SN + (cb0>>1));
        vr1 = *(const short8v*)(VtT + ((size_t)(b*EN)+h*DN+r1)*SN + (cb1>>1));
    }
    __syncthreads();

    int qlj = w*16 + ((lane>>4)<<2);
    float tsq_r[4]; int sgq_r[4]; float xr[4];
    float elk = expf(lk);
    #pragma unroll
    for (int j=0;j<4;j++){
        tsq_r[j]=tsq_s[qlj+j];
        sgq_r[j]=segq_s[qlj+j];
        xr[j] = (sgq_r[j]==0) ? elk : 0.f;
    }
    short8v aq0 = *(short8v*)((char*)Qs + swz(w*16+(lane&15), (lane>>4)*16));
    short8v aq1 = *(short8v*)((char*)Qs + swz(w*16+(lane&15), 64 + (lane>>4)*16));

    // cross term: oacc = xr * (Q' @ h0)   (xi/eq is block-uniform = elk)
    f32x4 oacc[4];
    {
        f32x4 cacc[4];
        #pragma unroll
        for (int en=0;en<4;en++){ cacc[en][0]=0.f; cacc[en][1]=0.f; cacc[en][2]=0.f; cacc[en][3]=0.f; }
        #pragma unroll
        for (int en=0;en<4;en++){
            short8v b0 = *(short8v*)((char*)Ps + swz(en*16+(lane&15), (lane>>4)*16));
            short8v b1 = *(short8v*)((char*)Ps + swz(en*16+(lane&15), 64+(lane>>4)*16));
            cacc[en] = __builtin_amdgcn_mfma_f32_16x16x32_bf16(aq0, b0, cacc[en], 0,0,0);
            cacc[en] = __builtin_amdgcn_mfma_f32_16x16x32_bf16(aq1, b1, cacc[en], 0,0,0);
        }
        #pragma unroll
        for (int en=0;en<4;en++)
            #pragma unroll
            for (int j=0;j<4;j++) oacc[en][j] = cacc[en][j]*xr[j];
    }

    for (int mt=0; mt<=tile; ++mt){
        int m0 = mt*64;
        __syncthreads();   // previous readers of Ks/Vts (and Ps cross-term) done
        {   // write prefetched regs -> LDS (swizzled)
            int c0 = t, c1 = t+256;
            int r0=c0>>3, cb0=(c0&7)*16, r1=c1>>3, cb1=(c1&7)*16;
            *(short8v*)((char*)Ks  + swz(r0,cb0)) = kr0;
            *(short8v*)((char*)Ks  + swz(r1,cb1)) = kr1;
            *(short8v*)((char*)Vts + swz(r0,cb0)) = vr0;
            *(short8v*)((char*)Vts + swz(r1,cb1)) = vr1;
        }
        if (t<64){
            tsm_s[t] = (float)tsid[b*SN+m0+t];
            segm_s[t] = seg[b*SN+m0+t];
        }
        if (mt < tile){   // prefetch next m-tile (flies under the MFMA phase)
            int m1 = m0 + 64;
            int c0 = t, c1 = t+256;
            int r0=c0>>3, cb0=(c0&7)*16, r1=c1>>3, cb1=(c1&7)*16;
            kr0 = *(const short8v*)(Kbb + (size_t)(b*SN+m1+r0)*EN + h*DN + (cb0>>1));
            kr1 = *(const short8v*)(Kbb + (size_t)(b*SN+m1+r1)*EN + h*DN + (cb1>>1));
            vr0 = *(const short8v*)(VtT + ((size_t)(b*EN)+h*DN+r0)*SN + m1 + (cb0>>1));
            vr1 = *(const short8v*)(VtT + ((size_t)(b*EN)+h*DN+r1)*SN + m1 + (cb1>>1));
        }
        __syncthreads();
        // S = Q' @ K'^T  (decay already folded in)
        f32x4 sacc[4];
        #pragma unroll
        for (int mn=0;mn<4;mn++){ sacc[mn][0]=0.f; sacc[mn][1]=0.f; sacc[mn][2]=0.f; sacc[mn][3]=0.f; }
        __builtin_amdgcn_s_setprio(1);
        #pragma unroll
        for (int mn=0;mn<4;mn++){
            short8v b0 = *(short8v*)((char*)Ks + swz(mn*16+(lane&15), (lane>>4)*16));
            short8v b1 = *(short8v*)((char*)Ks + swz(mn*16+(lane&15), 64+(lane>>4)*16));
            sacc[mn] = __builtin_amdgcn_mfma_f32_16x16x32_bf16(aq0, b0, sacc[mn], 0,0,0);
            sacc[mn] = __builtin_amdgcn_mfma_f32_16x16x32_bf16(aq1, b1, sacc[mn], 0,0,0);
        }
        __builtin_amdgcn_s_setprio(0);
        // mask + cvt: dt>=0 automatic off-diagonal (ts non-decreasing)
        if (mt==tile){
            #pragma unroll
            for (int mn=0;mn<4;mn++){
                int m = mn*16 + (lane&15);
                int sgm = segm_s[m];
                float tm = tsm_s[m];
                #pragma unroll
                for (int j=0;j<4;j++){
                    float p = (tsq_r[j]>=tm && sgq_r[j]==sgm) ? sacc[mn][j] : 0.f;
                    *(u16*)((char*)Ps + swz(qlj+j, 2*m)) = f2bf(p);
                }
            }
        } else {
            #pragma unroll
            for (int mn=0;mn<4;mn++){
                int m = mn*16 + (lane&15);
                int sgm = segm_s[m];
                #pragma unroll
                for (int j=0;j<4;j++){
                    float p = (sgq_r[j]==sgm) ? sacc[mn][j] : 0.f;
                    *(u16*)((char*)Ps + swz(qlj+j, 2*m)) = f2bf(p);
                }
            }
        }
        // PV accumulate (A-frags from own strip — intra-wave dependency only)
        short8v ap0 = *(short8v*)((char*)Ps + swz(w*16+(lane&15), (lane>>4)*16));
        short8v ap1 = *(short8v*)((char*)Ps + swz(w*16+(lane&15), 64+(lane>>4)*16));
        __builtin_amdgcn_s_setprio(1);
        #pragma unroll
        for (int dn=0;dn<4;dn++){
            short8v b0 = *(short8v*)((char*)Vts + swz(dn*16+(lane&15), (lane>>4)*16));
            short8v b1 = *(short8v*)((char*)Vts + swz(dn*16+(lane&15), 64+(lane>>4)*16));
            oacc[dn] = __builtin_amdgcn_mfma_f32_16x16x32_bf16(ap0, b0, oacc[dn], 0,0,0);
            oacc[dn] = __builtin_amdgcn_mfma_f32_16x16x32_bf16(ap1, b1, oacc[dn], 0,0,0);
        }
        __builtin_amdgcn_s_setprio(0);
    }

    // fused groupnorm + gate multiply
    float mu[4], rs[4];
    #pragma unroll
    for (int j=0;j<4;j++){
        float s = oacc[0][j]+oacc[1][j]+oacc[2][j]+oacc[3][j];
        #pragma unroll
        for (int off=1; off<16; off<<=1) s += __shfl_xor(s, off, 64);
        mu[j] = s*(1.0f/64.0f);
        float d0=oacc[0][j]-mu[j], d1=oacc[1][j]-mu[j], d2=oacc[2][j]-mu[j], d3=oacc[3][j]-mu[j];
        float q2 = d0*d0+d1*d1+d2*d2+d3*d3;
        #pragma unroll
        for (int off=1; off<16; off<<=1) q2 += __shfl_xor(q2, off, 64);
        rs[j] = rsqrtf(q2*(1.0f/64.0f) + EPSF);
    }
    #pragma unroll
    for (int dn=0;dn<4;dn++){
        int e = h*DN + dn*16 + (lane&15);
        float gs = gns[e], gb = gnb[e];
        #pragma unroll
        for (int j=0;j<4;j++){
            size_t row = (size_t)(b*SN + n0 + qlj + j);
            float y = (oacc[dn][j]-mu[j])*rs[j]*gs + gb;
            Out[row*EN + e] = f2bf(y * bf2f(Gb[row*EN + e]));
        }
    }
}

// ---------------- v_loc = ZN @ w2 + b2 (M=1) ----------------
__global__ void vloc_kernel(const float* __restrict__ ZN, const float* __restrict__ w2,
                            const float* __restrict__ b2, float* __restrict__ out){
    int row  = blockIdx.x*4 + (threadIdx.x>>6);
    int lane = threadIdx.x & 63;
    const float* z = ZN + (size_t)row*EN;
    float s = 0.f;
    #pragma unroll
    for (int i=0;i<8;i++) s += z[lane + i*64]*w2[lane + i*64];
    #pragma unroll
    for (int off=32; off>0; off>>=1) s += __shfl_xor(s, off, 64);
    if (lane==0) out[row] = s + b2[0];
}

// ---------------- host ----------------
static inline void launch_gemm(const u16* A, const u16* Wt, const float* bias,
                               const u16* res, float* C, u16* Ob,
                               int K, float scale, int act, int outm, hipStream_t s){
    dim3 g(8, 32), b(512,1,1);
    if (bias)                    gemm_bf16<2,true ,false,1><<<g,b,0,s>>>(A,Wt,bias,res,C,Ob,K,scale);
    else if (res && outm==3)     gemm_bf16<0,false,true ,3><<<g,b,0,s>>>(A,Wt,bias,res,C,Ob,K,scale);
    else if (res)                gemm_bf16<0,false,true ,1><<<g,b,0,s>>>(A,Wt,bias,res,C,Ob,K,scale);
    else if (act==2)             gemm_bf16<2,false,false,1><<<g,b,0,s>>>(A,Wt,bias,res,C,Ob,K,scale);
    else                         gemm_bf16<0,false,false,1><<<g,b,0,s>>>(A,Wt,bias,res,C,Ob,K,scale);
}

extern "C" void kernel_launch(void* const* d_in, const int* in_sizes, int n_in,
                              void* d_out, int out_size, void* d_ws, size_t ws_size,
                              hipStream_t stream){
    const float* obs       = (const float*)d_in[0];
    const float* hstate    = (const float*)d_in[1];
    const int*   dones     = (const int*)  d_in[2];
    const int*   tsid      = (const int*)  d_in[3];
    const float* ln_enc    = (const float*)d_in[4];
    const float* w_enc     = (const float*)d_in[5];
    const float* ln_shared = (const float*)d_in[6];
    const float* wq        = (const float*)d_in[7];
    const float* wk        = (const float*)d_in[8];
    const float* wv        = (const float*)d_in[9];
    const float* wg        = (const float*)d_in[10];
    const float* wo        = (const float*)d_in[11];
    const float* gns       = (const float*)d_in[12];
    const float* gnb       = (const float*)d_in[13];
    const float* ln1       = (const float*)d_in[14];
    const float* ln2       = (const float*)d_in[15];
    const float* swg       = (const float*)d_in[16];
    const float* swl       = (const float*)d_in[17];
    const float* swo       = (const float*)d_in[18];
    const float* hw1       = (const float*)d_in[19];
    const float* hb1       = (const float*)d_in[20];
    const float* hln       = (const float*)d_in[21];
    const float* hw2       = (const float*)d_in[22];
    const float* hb2       = (const float*)d_in[23];

    float* out_v = (float*)d_out;                 // (B,S,1)
    float* out_x = out_v + NR;                    // (B,S,E)
    float* out_h = out_x + (size_t)NR*EN;         // (B,H,L,D,D)

    float* ws    = (float*)d_ws;
    float* XIN   = ws + 0*(size_t)NB;   // (unused; layout stability)
    float* Qb    = ws + 1*(size_t)NB;   // f32 temp; VtT+KtT alias it
    float* Kb    = ws + 2*(size_t)NB;   // Qf temp
    float* Vb    = ws + 3*(size_t)NB;   // (spare)
    float* Gbf   = ws + 4*(size_t)NB;   // hosts bf16 gate (4 MB used)
    float* Yb    = ws + 5*(size_t)NB;
    int*   seg   = (int*)(ws + 6*(size_t)NB);
    u16* wtb  = (u16*)(seg + NR);
    const size_t WEm = (size_t)EN*EN;
    u16* wqT   = wtb;                 // type 0
    u16* wkT   = wqT + 4*WEm;         // type 1
    u16* wvT   = wkT + 4*WEm;         // type 2
    u16* wgT   = wvT + 4*WEm;         // type 3
    u16* woT   = wgT + 4*WEm;         // type 4
    u16* sgT   = woT + 4*WEm;         // type 5
    u16* slT   = sgT + 4*WEm;         // type 6
    u16* soT   = slT + 4*WEm;         // type 7
    u16* wencT = soT + 4*WEm;
    u16* w1T   = wencT + (size_t)EN*OBSN;
    u16* S1b   = w1T + WEm;
    u16* S2b   = S1b + (size_t)NB;
    u16* encb  = S2b + (size_t)NB;
    u16* Qbb   = encb + (size_t)NR*OBSN;
    u16* Kbb   = Qbb + (size_t)NB;
    u16* VtT   = (u16*)Qb;             // bf16 V^T [B][512][S]  (4 MB)
    u16* KtT   = VtT + (size_t)NB;     // bf16 K^T [B][512][S]  (4 MB)
    u16* Gb16  = (u16*)Gbf;            // bf16 gate (4 MB)
    float* Qf  = Kb;                   // f32 temp for wo/swo outputs

    seg_kernel<<<BN, SN, 0, stream>>>(dones, seg);

    {
        dim3 tb(32,8,1);
        wconv8_kernel<<<dim3(16,16,32), tb, 0, stream>>>(wq,wk,wv,wg,wo,swg,swl,swo, wtb);
        wconv_kernel<<<dim3(16,4,1),  tb, 0, stream>>>(w_enc, wencT, OBSN, EN);
        wconv_kernel<<<dim3(16,16,1), tb, 0, stream>>>(hw1,   w1T,   EN, EN);
    }

    // encoder
    rmsnorm_kernel<OBSN,false,true><<<NR/4, 256, 0, stream>>>(obs, ln_enc, nullptr, encb);
    launch_gemm(encb, wencT, nullptr, nullptr, out_x, nullptr, OBSN, 1.f, 2, 1, stream);

    for (int l=0; l<LN; ++l){
        rmsnorm_kernel<EN,false,true><<<NR/4, 256, 0, stream>>>(out_x, ln_shared, nullptr, S1b); // xin bf16
        gemm_qkvg<<<dim3(8,32), 512, 0, stream>>>(S1b,
            wqT + l*WEm, wkT + l*WEm, wvT + l*WEm, wgT + l*WEm, tsid,
            Qbb, Kbb, VtT, KtT, Gb16);
        retention_mfma<<<dim3(17, BN*HN), 256, 0, stream>>>(
            Qbb, Kbb, VtT, KtT, hstate, tsid, seg, gns + l*EN, gnb + l*EN,
            Gb16, S2b, out_h, l);
        launch_gemm(S2b, woT + l*WEm, nullptr, S1b, Qf, nullptr, EN, 1.f, 0, 1, stream); // Qf = ret@wo + xin(bf16)
        rmsnorm_kernel<EN,false,true><<<NR/4, 256, 0, stream>>>(Qf, ln1 + l*EN, nullptr, S1b); // x1 bf16
        gemm_swpair<<<dim3(8,32), 512, 0, stream>>>(S1b, sgT + l*WEm, slT + l*WEm, S2b);
        launch_gemm(S2b, soT + l*WEm, nullptr, S1b, Qf, nullptr, EN, 1.f, 0, 1, stream);  // Qf = t@swo + x1(bf16)
        if (l == LN-1)
            rmsnorm_kernel<EN,true,true ><<<NR/4, 256, 0, stream>>>(Qf, ln2 + l*EN, out_x, S1b);
        else
            rmsnorm_kernel<EN,true,false><<<NR/4, 256, 0, stream>>>(Qf, ln2 + l*EN, out_x, nullptr);
    }

    // head
    launch_gemm(S1b, w1T, hb1, nullptr, Yb, nullptr, EN, 1.f, 2, 1, stream);
    rmsnorm_kernel<EN,true,false><<<NR/4, 256, 0, stream>>>(Yb, hln, XIN, nullptr);
    vloc_kernel<<<NR/4, 256, 0, stream>>>(XIN, hw2, hb2, out_v);
}

// Round 11
// 425.512 us; speedup vs baseline: 1.0542x; 1.0542x over previous
//
#include <hip/hip_runtime.h>
#include <math.h>

#define BN 4
#define SN 1024
#define EN 512
#define HN 8
#define LN 4
#define DN 64
#define OBSN 128
#define NR (BN*SN)            // 4096 rows
#define NB (NR*EN)            // elements per activation buffer
#define EPSF 1e-6f

typedef __attribute__((ext_vector_type(8))) short short8v;
typedef __attribute__((ext_vector_type(4))) float f32x4;
typedef unsigned short u16;

__device__ __forceinline__ float logk_of(int h){
    const float start = -3.4657359027997265f;   // log(1/32)
    const float step  = -0.3960841031771117f;   // (log(1/512)-log(1/32))/7
    return logf(1.0f - expf(start + step*(float)h));
}
__device__ __forceinline__ float geluf(float x){
    float x3 = x*x*x;
    return 0.5f*x*(1.0f + tanhf(0.7978845608028654f*(x + 0.044715f*x3)));
}
__device__ __forceinline__ float siluf(float x){
    return x / (1.0f + expf(-x));
}
__device__ __forceinline__ u16 f2bf(float x){
    union { float f; unsigned u; } v; v.f = x;
    unsigned r = v.u + 0x7FFFu + ((v.u >> 16) & 1u);
    return (u16)(r >> 16);
}
__device__ __forceinline__ float bf2f(u16 x){
    union { unsigned u; float f; } v; v.u = ((unsigned)x)<<16;
    return v.f;
}
__device__ __forceinline__ void load_lds16(const void* g, void* l){
    __builtin_amdgcn_global_load_lds((const __attribute__((address_space(1))) void*)g,
                                     (__attribute__((address_space(3))) void*)l, 16, 0, 0);
}
// XOR swizzle for 64-row x 128B LDS tiles
__device__ __forceinline__ int swz(int r, int bo){ return r*128 + (bo ^ ((r&7)<<4)); }

// ---------------- segment cumsum (inclusive) ----------------
__global__ void seg_kernel(const int* __restrict__ dones, int* __restrict__ seg){
    __shared__ int sm[SN];
    int b = blockIdx.x, t = threadIdx.x;
    sm[t] = dones[b*SN + t];
    __syncthreads();
    for (int off=1; off<SN; off<<=1){
        int v = (t>=off) ? sm[t-off] : 0;
        __syncthreads();
        sm[t] += v;
        __syncthreads();
    }
    seg[b*SN + t] = sm[t];
}

// ---------------- weight convert+transpose: f32 [K][M] -> bf16 [M][K] ----------------
__global__ void wconv8_kernel(const float* w0, const float* w1, const float* w2,
                              const float* w3, const float* w4, const float* w5,
                              const float* w6, const float* w7,
                              u16* __restrict__ dst){
    __shared__ u16 tile[32][33];
    int z = blockIdx.z;
    int type = z>>2, layer = z&3;
    const float* srcs[8] = {w0,w1,w2,w3,w4,w5,w6,w7};
    const float* s = srcs[type] + (size_t)layer*EN*EN;
    u16* d = dst + ((size_t)type*LN + layer)*EN*EN;
    int k0 = blockIdx.y*32, m0 = blockIdx.x*32;
    int tx = threadIdx.x, ty = threadIdx.y;   // 32, 8
    #pragma unroll
    for (int i=0;i<32;i+=8)
        tile[tx][ty+i] = f2bf(s[(size_t)(k0+ty+i)*EN + m0+tx]);
    __syncthreads();
    #pragma unroll
    for (int i=0;i<32;i+=8)
        d[(size_t)(m0+ty+i)*EN + k0+tx] = tile[ty+i][tx];
}
__global__ void wconv_kernel(const float* __restrict__ src, u16* __restrict__ dst,
                             int K, int M){
    __shared__ u16 tile[32][33];
    int k0 = blockIdx.y*32, m0 = blockIdx.x*32;
    int tx = threadIdx.x, ty = threadIdx.y;
    #pragma unroll
    for (int i=0;i<32;i+=8)
        tile[tx][ty+i] = f2bf(src[(size_t)(k0+ty+i)*M + m0+tx]);
    __syncthreads();
    #pragma unroll
    for (int i=0;i<32;i+=8)
        dst[(size_t)(m0+ty+i)*K + k0+tx] = tile[ty+i][tx];
}

// ---------------- rmsnorm (one wave per row), optional f32 + bf16 outputs ----------------
template<int COLS, bool WF32, bool WBF>
__global__ void rmsnorm_kernel(const float* __restrict__ A,
                               const float* __restrict__ scale,
                               float* __restrict__ Of,
                               u16* __restrict__ Ob){
    constexpr int PER = COLS/64;
    int row  = blockIdx.x*4 + (threadIdx.x>>6);
    int lane = threadIdx.x & 63;
    const float* a = A + (size_t)row*COLS;
    float v[PER];
    float ss = 0.f;
    #pragma unroll
    for (int i=0;i<PER;i++){
        float x = a[lane + i*64];
        v[i] = x; ss += x*x;
    }
    #pragma unroll
    for (int off=32; off>0; off>>=1) ss += __shfl_xor(ss, off, 64);
    float rs = rsqrtf(ss*(1.0f/COLS) + EPSF);
    #pragma unroll
    for (int i=0;i<PER;i++){
        float o = v[i]*rs*scale[lane + i*64];
        if (WF32) Of[(size_t)row*COLS + lane + i*64] = o;
        if (WBF)  Ob[(size_t)row*COLS + lane + i*64] = f2bf(o);
    }
}

// ======== shared MFMA tile helpers (BM=BN=64, BK=64, 256 thr, 4 waves 2x2) ========
__device__ __forceinline__ void stage_tile(const u16* __restrict__ G, size_t rowBase,
                                           int K, int k0, u16* dst, int t){
    #pragma unroll
    for (int i=0;i<2;i++){
        int o = i*4096 + t*16;
        int grow = o>>7, gcolb = o&127;
        load_lds16(G + (rowBase+grow)*K + k0 + (gcolb>>1), (char*)dst + o);
    }
}
__device__ __forceinline__ void mma_tile(const u16* As, const u16* Bs, f32x4 acc[2][2],
                                         int wr, int wc, int lane){
    #pragma unroll
    for (int kk=0; kk<64; kk+=32){
        int kb = kk + (lane>>4)*8;
        short8v a[2], b[2];
        #pragma unroll
        for (int m=0;m<2;m++)
            a[m] = *(const short8v*)((const char*)As + (wr*32+m*16+(lane&15))*128 + kb*2);
        #pragma unroll
        for (int n=0;n<2;n++)
            b[n] = *(const short8v*)((const char*)Bs + (wc*32+n*16+(lane&15))*128 + kb*2);
        #pragma unroll
        for (int m=0;m<2;m++)
            #pragma unroll
            for (int n=0;n<2;n++)
                acc[m][n] = __builtin_amdgcn_mfma_f32_16x16x32_bf16(a[m], b[n], acc[m][n], 0,0,0);
    }
}
#define ZERO_ACC(acc) { _Pragma("unroll") for (int m=0;m<2;m++) _Pragma("unroll") for (int n=0;n<2;n++){ acc[m][n][0]=0.f;acc[m][n][1]=0.f;acc[m][n][2]=0.f;acc[m][n][3]=0.f; } }

// ---------------- fused QKVG GEMM (2-phase pipelined, decay-prescaled Q/K epilogue) ----------------
__global__ __launch_bounds__(256) void gemm_qkvg(
    const u16* __restrict__ A,
    const u16* __restrict__ WQ, const u16* __restrict__ WK,
    const u16* __restrict__ WV, const u16* __restrict__ WG,
    const int* __restrict__ tsid,
    u16* __restrict__ Qbb, u16* __restrict__ Kbb,
    u16* __restrict__ VtT, u16* __restrict__ KtT, u16* __restrict__ Gb)
{
    __shared__ u16 As[2][64*64];
    __shared__ u16 Bs[2][4][64*64];
    int t = threadIdx.x;
    int row0 = blockIdx.y*64, col0 = blockIdx.x*64;
    int w = t>>6, lane = t&63;
    int wr = w>>1, wc = w&1;
    f32x4 accQ[2][2], accK[2][2], accV[2][2], accG[2][2];
    ZERO_ACC(accQ); ZERO_ACC(accK); ZERO_ACC(accV); ZERO_ACC(accG);
    const u16* Ws[4] = {WQ, WK, WV, WG};

    stage_tile(A, (size_t)row0, EN, 0, As[0], t);
    #pragma unroll
    for (int wt=0; wt<4; wt++) stage_tile(Ws[wt], (size_t)col0, EN, 0, Bs[0][wt], t);
    __syncthreads();
    for (int ti=0; ti<EN/64; ++ti){
        int cur = ti&1;
        if (ti+1 < EN/64){
            stage_tile(A, (size_t)row0, EN, (ti+1)*64, As[cur^1], t);
            #pragma unroll
            for (int wt=0; wt<4; wt++)
                stage_tile(Ws[wt], (size_t)col0, EN, (ti+1)*64, Bs[cur^1][wt], t);
        }
        mma_tile(As[cur], Bs[cur][0], accQ, wr, wc, lane);
        mma_tile(As[cur], Bs[cur][1], accK, wr, wc, lane);
        mma_tile(As[cur], Bs[cur][2], accV, wr, wc, lane);
        mma_tile(As[cur], Bs[cur][3], accG, wr, wc, lane);
        __syncthreads();
    }
    // decay pre-scale: col tile == head (grid.x = 8)
    float lk = logk_of(blockIdx.x);
    float eqv[2][4], emv[2][4];
    #pragma unroll
    for (int m=0;m<2;m++)
        #pragma unroll
        for (int j=0;j<4;j++){
            int row = row0 + wr*32 + m*16 + (lane>>4)*4 + j;
            float tq = (float)tsid[row];
            eqv[m][j] = expf(tq*lk);
            emv[m][j] = expf(-tq*lk);
        }
    #pragma unroll
    for (int m=0;m<2;m++){
        #pragma unroll
        for (int n=0;n<2;n++){
            int col = col0 + wc*32 + n*16 + (lane&15);
            int rbase = row0 + wr*32 + m*16 + (lane>>4)*4;
            ushort4 pkV, pkK;
            #pragma unroll
            for (int j=0;j<4;j++){
                size_t idx = (size_t)(rbase+j)*EN + col;
                Qbb[idx] = f2bf(eqv[m][j]*accQ[m][n][j]);
                float kx = emv[m][j]*0.125f*accK[m][n][j];
                Kbb[idx] = f2bf(kx);
                ((u16*)&pkK)[j] = f2bf(kx);
                ((u16*)&pkV)[j] = f2bf(accV[m][n][j]);
                Gb[idx] = f2bf(siluf(accG[m][n][j]));
            }
            int bb = rbase>>10;
            int s0 = rbase&1023;
            *(ushort4*)(VtT + ((size_t)bb*EN + col)*SN + s0) = pkV;
            *(ushort4*)(KtT + ((size_t)bb*EN + col)*SN + s0) = pkK;
        }
    }
}

// ---------------- fused swiglu pair (2-phase): Out = bf16(silu(A@Wg)*(A@Wl)) ----------------
__global__ __launch_bounds__(256) void gemm_swpair(
    const u16* __restrict__ A,
    const u16* __restrict__ WGt, const u16* __restrict__ WLt,
    u16* __restrict__ Out)
{
    __shared__ u16 As[2][64*64];
    __shared__ u16 Bg[2][64*64];
    __shared__ u16 Bl[2][64*64];
    int t = threadIdx.x;
    int row0 = blockIdx.y*64, col0 = blockIdx.x*64;
    int w = t>>6, lane = t&63;
    int wr = w>>1, wc = w&1;
    f32x4 accG[2][2], accL[2][2];
    ZERO_ACC(accG); ZERO_ACC(accL);
    stage_tile(A, (size_t)row0, EN, 0, As[0], t);
    stage_tile(WGt, (size_t)col0, EN, 0, Bg[0], t);
    stage_tile(WLt, (size_t)col0, EN, 0, Bl[0], t);
    __syncthreads();
    for (int ti=0; ti<EN/64; ++ti){
        int cur = ti&1;
        if (ti+1 < EN/64){
            stage_tile(A, (size_t)row0, EN, (ti+1)*64, As[cur^1], t);
            stage_tile(WGt, (size_t)col0, EN, (ti+1)*64, Bg[cur^1], t);
            stage_tile(WLt, (size_t)col0, EN, (ti+1)*64, Bl[cur^1], t);
        }
        mma_tile(As[cur], Bg[cur], accG, wr, wc, lane);
        mma_tile(As[cur], Bl[cur], accL, wr, wc, lane);
        __syncthreads();
    }
    #pragma unroll
    for (int m=0;m<2;m++){
        #pragma unroll
        for (int n=0;n<2;n++){
            int col = col0 + wc*32 + n*16 + (lane&15);
            int rbase = row0 + wr*32 + m*16 + (lane>>4)*4;
            #pragma unroll
            for (int j=0;j<4;j++){
                float x = siluf(accG[m][n][j]) * accL[m][n][j];
                Out[(size_t)(rbase+j)*EN + col] = f2bf(x);
            }
        }
    }
}

// ---------------- plain bf16 GEMM (2-phase; residual read as bf16) ----------------
template<int ACT, bool BIASF, bool RESF, int OUTM>
__global__ __launch_bounds__(256) void gemm_bf16(
    const u16* __restrict__ A, const u16* __restrict__ Wt,
    const float* __restrict__ bias, const u16* __restrict__ res,
    float* __restrict__ C, u16* __restrict__ Ob, int K, float scale)
{
    __shared__ u16 As[2][64*64];
    __shared__ u16 Bs[2][64*64];
    int t = threadIdx.x;
    int row0 = blockIdx.y*64, col0 = blockIdx.x*64;
    int w = t>>6, lane = t&63;
    int wr = w>>1, wc = w&1;
    f32x4 acc[2][2];
    ZERO_ACC(acc);
    int nt = K/64;
    stage_tile(A, (size_t)row0, K, 0, As[0], t);
    stage_tile(Wt, (size_t)col0, K, 0, Bs[0], t);
    __syncthreads();
    for (int ti=0; ti<nt; ++ti){
        int cur = ti&1;
        if (ti+1 < nt){
            stage_tile(A, (size_t)row0, K, (ti+1)*64, As[cur^1], t);
            stage_tile(Wt, (size_t)col0, K, (ti+1)*64, Bs[cur^1], t);
        }
        mma_tile(As[cur], Bs[cur], acc, wr, wc, lane);
        __syncthreads();
    }
    #pragma unroll
    for (int m=0;m<2;m++){
        #pragma unroll
        for (int n=0;n<2;n++){
            int col = col0 + wc*32 + n*16 + (lane&15);
            int rbase = row0 + wr*32 + m*16 + (lane>>4)*4;
            #pragma unroll
            for (int j=0;j<4;j++){
                float x = acc[m][n][j]*scale;
                if (BIASF) x += bias[col];
                if (ACT==1) x = siluf(x);
                if (ACT==2) x = geluf(x);
                if (RESF) x += bf2f(res[(size_t)(rbase+j)*512 + col]);
                if (OUTM&1) C[(size_t)(rbase+j)*512 + col] = x;
                if (OUTM&2) Ob[(size_t)(rbase+j)*512 + col] = f2bf(x);
            }
        }
    }
}

// ---------------- MFMA retention (decay-prescaled) + groupnorm + gate-mul + fused h_new ----------------
// grid (17, B*H): blockIdx.x==0 -> h_new role; else q-tile = 16-blockIdx.x (heavy first).
__global__ __launch_bounds__(256) void retention_mfma(
    const u16* __restrict__ Qbb, const u16* __restrict__ Kbb,
    const u16* __restrict__ VtT, const u16* __restrict__ KtT,
    const float* __restrict__ hstate, const int* __restrict__ tsid, const int* __restrict__ seg,
    const float* __restrict__ gns, const float* __restrict__ gnb,
    const u16* __restrict__ Gb, u16* __restrict__ Out,
    float* __restrict__ Hout, int layer)
{
    int bh = blockIdx.y; int b = bh>>3; int h = bh&7;
    int t = threadIdx.x, lane = t&63, w = t>>6;
    __shared__ u16 Qs[64*64];
    __shared__ u16 Ks[64*64];
    __shared__ u16 Vts[64*64];
    __shared__ u16 Ps[64*64];
    __shared__ float tsq_s[64];
    __shared__ int   segq_s[64];
    __shared__ float tsm_s[64];
    __shared__ int   segm_s[64];
    float lk = logk_of(h);

    if (blockIdx.x == 0){
        // ---- h_new role: ho = h0*hd + cfac * sum_m (K'[m] & mask) (x) V[m] ----
        float tmax = (float)tsid[b*SN + SN-1];
        int segl = seg[b*SN + SN-1];
        u16* m16 = Qs;          // 1024-entry 0xFFFF/0 mask in Qs region
        #pragma unroll
        for (int i=0;i<4;i++){
            int m = t + i*256;
            m16[m] = (seg[b*SN+m]==segl) ? (u16)0xFFFFu : (u16)0;
        }
        f32x4 eacc[4];
        #pragma unroll
        for (int en=0;en<4;en++){ eacc[en][0]=0.f; eacc[en][1]=0.f; eacc[en][2]=0.f; eacc[en][3]=0.f; }
        for (int mt=0; mt<16; ++mt){
            int m0 = mt*64;
            __syncthreads();
            #pragma unroll
            for (int i=0;i<2;i++){
                int c = t + i*256; int r = c>>3, cb = (c&7)*16;
                int mb = m0 + (cb>>1);
                size_t g = ((size_t)(b*EN) + h*DN + r)*SN + mb;
                short8v kt = *(const short8v*)(KtT + g);
                short8v vt = *(const short8v*)(VtT + g);
                short8v mv = *(const short8v*)(m16 + mb);
                kt &= mv;
                *(short8v*)((char*)Ks  + swz(r,cb)) = kt;
                *(short8v*)((char*)Vts + swz(r,cb)) = vt;
            }
            __syncthreads();
            short8v a0 = *(short8v*)((char*)Ks + swz(w*16+(lane&15), (lane>>4)*16));
            short8v a1 = *(short8v*)((char*)Ks + swz(w*16+(lane&15), 64+(lane>>4)*16));
            __builtin_amdgcn_s_setprio(1);
            #pragma unroll
            for (int en=0;en<4;en++){
                short8v b0 = *(short8v*)((char*)Vts + swz(en*16+(lane&15), (lane>>4)*16));
                short8v b1 = *(short8v*)((char*)Vts + swz(en*16+(lane&15), 64+(lane>>4)*16));
                eacc[en] = __builtin_amdgcn_mfma_f32_16x16x32_bf16(a0, b0, eacc[en], 0,0,0);
                eacc[en] = __builtin_amdgcn_mfma_f32_16x16x32_bf16(a1, b1, eacc[en], 0,0,0);
            }
            __builtin_amdgcn_s_setprio(0);
        }
        float cfac = expf(tmax*lk);
        float hd = (segl==0) ? expf((tmax+1.0f)*lk) : 0.f;
        const float* h0 = hstate + ((size_t)bh*LN + layer)*4096;
        float* ho = Hout + ((size_t)bh*LN + layer)*4096;
        #pragma unroll
        for (int en=0;en<4;en++){
            int e = en*16 + (lane&15);
            #pragma unroll
            for (int j=0;j<4;j++){
                int d = w*16 + (lane>>4)*4 + j;
                ho[d*64 + e] = h0[d*64 + e]*hd + cfac*eacc[en][j];
            }
        }
        return;
    }

    // ---- retention role ----
    int tile = 16 - (int)blockIdx.x;   // 15..0, heavy first
    int n0 = tile*64;

    #pragma unroll
    for (int i=0;i<2;i++){
        int c = t + i*256; int r = c>>3, cb = (c&7)*16;
        short8v qv = *(const short8v*)(Qbb + (size_t)(b*SN + n0 + r)*EN + h*DN + (cb>>1));
        *(short8v*)((char*)Qs + swz(r,cb)) = qv;
    }
    const float* h0 = hstate + ((size_t)bh*LN + layer)*4096;
    #pragma unroll
    for (int i=0;i<4;i++){
        int idx = t + i*256; int d = idx>>4, e0 = (idx&15)*4;
        float4 hv = *(const float4*)(h0 + d*64 + e0);
        *(u16*)((char*)Ps + swz(e0+0, 2*d)) = f2bf(hv.x);
        *(u16*)((char*)Ps + swz(e0+1, 2*d)) = f2bf(hv.y);
        *(u16*)((char*)Ps + swz(e0+2, 2*d)) = f2bf(hv.z);
        *(u16*)((char*)Ps + swz(e0+3, 2*d)) = f2bf(hv.w);
    }
    if (t<64){
        tsq_s[t] = (float)tsid[b*SN+n0+t];
        segq_s[t] = seg[b*SN+n0+t];
    }
    // prefetch m-tile 0 K/V into registers
    short8v kr0, kr1, vr0, vr1;
    {
        int c0 = t, c1 = t+256;
        int r0=c0>>3, cb0=(c0&7)*16, r1=c1>>3, cb1=(c1&7)*16;
        kr0 = *(const short8v*)(Kbb + (size_t)(b*SN+r0)*EN + h*DN + (cb0>>1));
        kr1 = *(const short8v*)(Kbb + (size_t)(b*SN+r1)*EN + h*DN + (cb1>>1));
        vr0 = *(const short8v*)(VtT + ((size_t)(b*EN)+h*DN+r0)*SN + (cb0>>1));
        vr1 = *(const short8v*)(VtT + ((size_t)(b*EN)+h*DN+r1)*SN + (cb1>>1));
    }
    __syncthreads();

    int qlj = w*16 + ((lane>>4)<<2);
    float tsq_r[4]; int sgq_r[4]; float xr[4];
    float elk = expf(lk);
    #pragma unroll
    for (int j=0;j<4;j++){
        tsq_r[j]=tsq_s[qlj+j];
        sgq_r[j]=segq_s[qlj+j];
        xr[j] = (sgq_r[j]==0) ? elk : 0.f;
    }
    short8v aq0 = *(short8v*)((char*)Qs + swz(w*16+(lane&15), (lane>>4)*16));
    short8v aq1 = *(short8v*)((char*)Qs + swz(w*16+(lane&15), 64 + (lane>>4)*16));

    // cross term: oacc = xr * (Q' @ h0)   (xi/eq is block-uniform = elk)
    f32x4 oacc[4];
    {
        f32x4 cacc[4];
        #pragma unroll
        for (int en=0;en<4;en++){ cacc[en][0]=0.f; cacc[en][1]=0.f; cacc[en][2]=0.f; cacc[en][3]=0.f; }
        #pragma unroll
        for (int en=0;en<4;en++){
            short8v b0 = *(short8v*)((char*)Ps + swz(en*16+(lane&15), (lane>>4)*16));
            short8v b1 = *(short8v*)((char*)Ps + swz(en*16+(lane&15), 64+(lane>>4)*16));
            cacc[en] = __builtin_amdgcn_mfma_f32_16x16x32_bf16(aq0, b0, cacc[en], 0,0,0);
            cacc[en] = __builtin_amdgcn_mfma_f32_16x16x32_bf16(aq1, b1, cacc[en], 0,0,0);
        }
        #pragma unroll
        for (int en=0;en<4;en++)
            #pragma unroll
            for (int j=0;j<4;j++) oacc[en][j] = cacc[en][j]*xr[j];
    }

    for (int mt=0; mt<=tile; ++mt){
        int m0 = mt*64;
        __syncthreads();   // previous readers of Ks/Vts (and Ps cross-term) done
        {   // write prefetched regs -> LDS (swizzled)
            int c0 = t, c1 = t+256;
            int r0=c0>>3, cb0=(c0&7)*16, r1=c1>>3, cb1=(c1&7)*16;
            *(short8v*)((char*)Ks  + swz(r0,cb0)) = kr0;
            *(short8v*)((char*)Ks  + swz(r1,cb1)) = kr1;
            *(short8v*)((char*)Vts + swz(r0,cb0)) = vr0;
            *(short8v*)((char*)Vts + swz(r1,cb1)) = vr1;
        }
        if (t<64){
            tsm_s[t] = (float)tsid[b*SN+m0+t];
            segm_s[t] = seg[b*SN+m0+t];
        }
        if (mt < tile){   // prefetch next m-tile (flies under the MFMA phase)
            int m1 = m0 + 64;
            int c0 = t, c1 = t+256;
            int r0=c0>>3, cb0=(c0&7)*16, r1=c1>>3, cb1=(c1&7)*16;
            kr0 = *(const short8v*)(Kbb + (size_t)(b*SN+m1+r0)*EN + h*DN + (cb0>>1));
            kr1 = *(const short8v*)(Kbb + (size_t)(b*SN+m1+r1)*EN + h*DN + (cb1>>1));
            vr0 = *(const short8v*)(VtT + ((size_t)(b*EN)+h*DN+r0)*SN + m1 + (cb0>>1));
            vr1 = *(const short8v*)(VtT + ((size_t)(b*EN)+h*DN+r1)*SN + m1 + (cb1>>1));
        }
        __syncthreads();
        // S = Q' @ K'^T  (decay already folded in)
        f32x4 sacc[4];
        #pragma unroll
        for (int mn=0;mn<4;mn++){ sacc[mn][0]=0.f; sacc[mn][1]=0.f; sacc[mn][2]=0.f; sacc[mn][3]=0.f; }
        __builtin_amdgcn_s_setprio(1);
        #pragma unroll
        for (int mn=0;mn<4;mn++){
            short8v b0 = *(short8v*)((char*)Ks + swz(mn*16+(lane&15), (lane>>4)*16));
            short8v b1 = *(short8v*)((char*)Ks + swz(mn*16+(lane&15), 64+(lane>>4)*16));
            sacc[mn] = __builtin_amdgcn_mfma_f32_16x16x32_bf16(aq0, b0, sacc[mn], 0,0,0);
            sacc[mn] = __builtin_amdgcn_mfma_f32_16x16x32_bf16(aq1, b1, sacc[mn], 0,0,0);
        }
        __builtin_amdgcn_s_setprio(0);
        // mask + cvt: dt>=0 automatic off-diagonal (ts non-decreasing)
        if (mt==tile){
            #pragma unroll
            for (int mn=0;mn<4;mn++){
                int m = mn*16 + (lane&15);
                int sgm = segm_s[m];
                float tm = tsm_s[m];
                #pragma unroll
                for (int j=0;j<4;j++){
                    float p = (tsq_r[j]>=tm && sgq_r[j]==sgm) ? sacc[mn][j] : 0.f;
                    *(u16*)((char*)Ps + swz(qlj+j, 2*m)) = f2bf(p);
                }
            }
        } else {
            #pragma unroll
            for (int mn=0;mn<4;mn++){
                int m = mn*16 + (lane&15);
                int sgm = segm_s[m];
                #pragma unroll
                for (int j=0;j<4;j++){
                    float p = (sgq_r[j]==sgm) ? sacc[mn][j] : 0.f;
                    *(u16*)((char*)Ps + swz(qlj+j, 2*m)) = f2bf(p);
                }
            }
        }
        // PV accumulate (A-frags from own strip — intra-wave dependency only)
        short8v ap0 = *(short8v*)((char*)Ps + swz(w*16+(lane&15), (lane>>4)*16));
        short8v ap1 = *(short8v*)((char*)Ps + swz(w*16+(lane&15), 64+(lane>>4)*16));
        __builtin_amdgcn_s_setprio(1);
        #pragma unroll
        for (int dn=0;dn<4;dn++){
            short8v b0 = *(short8v*)((char*)Vts + swz(dn*16+(lane&15), (lane>>4)*16));
            short8v b1 = *(short8v*)((char*)Vts + swz(dn*16+(lane&15), 64+(lane>>4)*16));
            oacc[dn] = __builtin_amdgcn_mfma_f32_16x16x32_bf16(ap0, b0, oacc[dn], 0,0,0);
            oacc[dn] = __builtin_amdgcn_mfma_f32_16x16x32_bf16(ap1, b1, oacc[dn], 0,0,0);
        }
        __builtin_amdgcn_s_setprio(0);
    }

    // fused groupnorm + gate multiply
    float mu[4], rs[4];
    #pragma unroll
    for (int j=0;j<4;j++){
        float s = oacc[0][j]+oacc[1][j]+oacc[2][j]+oacc[3][j];
        #pragma unroll
        for (int off=1; off<16; off<<=1) s += __shfl_xor(s, off, 64);
        mu[j] = s*(1.0f/64.0f);
        float d0=oacc[0][j]-mu[j], d1=oacc[1][j]-mu[j], d2=oacc[2][j]-mu[j], d3=oacc[3][j]-mu[j];
        float q2 = d0*d0+d1*d1+d2*d2+d3*d3;
        #pragma unroll
        for (int off=1; off<16; off<<=1) q2 += __shfl_xor(q2, off, 64);
        rs[j] = rsqrtf(q2*(1.0f/64.0f) + EPSF);
    }
    #pragma unroll
    for (int dn=0;dn<4;dn++){
        int e = h*DN + dn*16 + (lane&15);
        float gs = gns[e], gb = gnb[e];
        #pragma unroll
        for (int j=0;j<4;j++){
            size_t row = (size_t)(b*SN + n0 + qlj + j);
            float y = (oacc[dn][j]-mu[j])*rs[j]*gs + gb;
            Out[row*EN + e] = f2bf(y * bf2f(Gb[row*EN + e]));
        }
    }
}

// ---------------- v_loc = ZN @ w2 + b2 (M=1) ----------------
__global__ void vloc_kernel(const float* __restrict__ ZN, const float* __restrict__ w2,
                            const float* __restrict__ b2, float* __restrict__ out){
    int row  = blockIdx.x*4 + (threadIdx.x>>6);
    int lane = threadIdx.x & 63;
    const float* z = ZN + (size_t)row*EN;
    float s = 0.f;
    #pragma unroll
    for (int i=0;i<8;i++) s += z[lane + i*64]*w2[lane + i*64];
    #pragma unroll
    for (int off=32; off>0; off>>=1) s += __shfl_xor(s, off, 64);
    if (lane==0) out[row] = s + b2[0];
}

// ---------------- host ----------------
static inline void launch_gemm(const u16* A, const u16* Wt, const float* bias,
                               const u16* res, float* C, u16* Ob,
                               int K, float scale, int act, int outm, hipStream_t s){
    dim3 g(8, 64), b(256,1,1);
    if (bias)                    gemm_bf16<2,true ,false,1><<<g,b,0,s>>>(A,Wt,bias,res,C,Ob,K,scale);
    else if (res && outm==3)     gemm_bf16<0,false,true ,3><<<g,b,0,s>>>(A,Wt,bias,res,C,Ob,K,scale);
    else if (res)                gemm_bf16<0,false,true ,1><<<g,b,0,s>>>(A,Wt,bias,res,C,Ob,K,scale);
    else if (act==2)             gemm_bf16<2,false,false,1><<<g,b,0,s>>>(A,Wt,bias,res,C,Ob,K,scale);
    else                         gemm_bf16<0,false,false,1><<<g,b,0,s>>>(A,Wt,bias,res,C,Ob,K,scale);
}

extern "C" void kernel_launch(void* const* d_in, const int* in_sizes, int n_in,
                              void* d_out, int out_size, void* d_ws, size_t ws_size,
                              hipStream_t stream){
    const float* obs       = (const float*)d_in[0];
    const float* hstate    = (const float*)d_in[1];
    const int*   dones     = (const int*)  d_in[2];
    const int*   tsid      = (const int*)  d_in[3];
    const float* ln_enc    = (const float*)d_in[4];
    const float* w_enc     = (const float*)d_in[5];
    const float* ln_shared = (const float*)d_in[6];
    const float* wq        = (const float*)d_in[7];
    const float* wk        = (const float*)d_in[8];
    const float* wv        = (const float*)d_in[9];
    const float* wg        = (const float*)d_in[10];
    const float* wo        = (const float*)d_in[11];
    const float* gns       = (const float*)d_in[12];
    const float* gnb       = (const float*)d_in[13];
    const float* ln1       = (const float*)d_in[14];
    const float* ln2       = (const float*)d_in[15];
    const float* swg       = (const float*)d_in[16];
    const float* swl       = (const float*)d_in[17];
    const float* swo       = (const float*)d_in[18];
    const float* hw1       = (const float*)d_in[19];
    const float* hb1       = (const float*)d_in[20];
    const float* hln       = (const float*)d_in[21];
    const float* hw2       = (const float*)d_in[22];
    const float* hb2       = (const float*)d_in[23];

    float* out_v = (float*)d_out;                 // (B,S,1)
    float* out_x = out_v + NR;                    // (B,S,E)
    float* out_h = out_x + (size_t)NR*EN;         // (B,H,L,D,D)

    float* ws    = (float*)d_ws;
    float* XIN   = ws + 0*(size_t)NB;   // (unused; layout stability)
    float* Qb    = ws + 1*(size_t)NB;   // f32 temp; VtT+KtT alias it
    float* Kb    = ws + 2*(size_t)NB;   // Qf temp
    float* Vb    = ws + 3*(size_t)NB;   // (spare)
    float* Gbf   = ws + 4*(size_t)NB;   // hosts bf16 gate (4 MB used)
    float* Yb    = ws + 5*(size_t)NB;
    int*   seg   = (int*)(ws + 6*(size_t)NB);
    u16* wtb  = (u16*)(seg + NR);
    const size_t WEm = (size_t)EN*EN;
    u16* wqT   = wtb;                 // type 0
    u16* wkT   = wqT + 4*WEm;         // type 1
    u16* wvT   = wkT + 4*WEm;         // type 2
    u16* wgT   = wvT + 4*WEm;         // type 3
    u16* woT   = wgT + 4*WEm;         // type 4
    u16* sgT   = woT + 4*WEm;         // type 5
    u16* slT   = sgT + 4*WEm;         // type 6
    u16* soT   = slT + 4*WEm;         // type 7
    u16* wencT = soT + 4*WEm;
    u16* w1T   = wencT + (size_t)EN*OBSN;
    u16* S1b   = w1T + WEm;
    u16* S2b   = S1b + (size_t)NB;
    u16* encb  = S2b + (size_t)NB;
    u16* Qbb   = encb + (size_t)NR*OBSN;
    u16* Kbb   = Qbb + (size_t)NB;
    u16* VtT   = (u16*)Qb;             // bf16 V^T [B][512][S]  (4 MB)
    u16* KtT   = VtT + (size_t)NB;     // bf16 K^T [B][512][S]  (4 MB)
    u16* Gb16  = (u16*)Gbf;            // bf16 gate (4 MB)
    float* Qf  = Kb;                   // f32 temp for wo/swo outputs

    seg_kernel<<<BN, SN, 0, stream>>>(dones, seg);

    {
        dim3 tb(32,8,1);
        wconv8_kernel<<<dim3(16,16,32), tb, 0, stream>>>(wq,wk,wv,wg,wo,swg,swl,swo, wtb);
        wconv_kernel<<<dim3(16,4,1),  tb, 0, stream>>>(w_enc, wencT, OBSN, EN);
        wconv_kernel<<<dim3(16,16,1), tb, 0, stream>>>(hw1,   w1T,   EN, EN);
    }

    // encoder
    rmsnorm_kernel<OBSN,false,true><<<NR/4, 256, 0, stream>>>(obs, ln_enc, nullptr, encb);
    launch_gemm(encb, wencT, nullptr, nullptr, out_x, nullptr, OBSN, 1.f, 2, 1, stream);

    for (int l=0; l<LN; ++l){
        rmsnorm_kernel<EN,false,true><<<NR/4, 256, 0, stream>>>(out_x, ln_shared, nullptr, S1b); // xin bf16
        gemm_qkvg<<<dim3(8,64), 256, 0, stream>>>(S1b,
            wqT + l*WEm, wkT + l*WEm, wvT + l*WEm, wgT + l*WEm, tsid,
            Qbb, Kbb, VtT, KtT, Gb16);
        retention_mfma<<<dim3(17, BN*HN), 256, 0, stream>>>(
            Qbb, Kbb, VtT, KtT, hstate, tsid, seg, gns + l*EN, gnb + l*EN,
            Gb16, S2b, out_h, l);
        launch_gemm(S2b, woT + l*WEm, nullptr, S1b, Qf, nullptr, EN, 1.f, 0, 1, stream); // Qf = ret@wo + xin(bf16)
        rmsnorm_kernel<EN,false,true><<<NR/4, 256, 0, stream>>>(Qf, ln1 + l*EN, nullptr, S1b); // x1 bf16
        gemm_swpair<<<dim3(8,64), 256, 0, stream>>>(S1b, sgT + l*WEm, slT + l*WEm, S2b);
        launch_gemm(S2b, soT + l*WEm, nullptr, S1b, Qf, nullptr, EN, 1.f, 0, 1, stream);  // Qf = t@swo + x1(bf16)
        if (l == LN-1)
            rmsnorm_kernel<EN,true,true ><<<NR/4, 256, 0, stream>>>(Qf, ln2 + l*EN, out_x, S1b);
        else
            rmsnorm_kernel<EN,true,false><<<NR/4, 256, 0, stream>>>(Qf, ln2 + l*EN, out_x, nullptr);
    }

    // head
    launch_gemm(S1b, w1T, hb1, nullptr, Yb, nullptr, EN, 1.f, 2, 1, stream);
    rmsnorm_kernel<EN,true,false><<<NR/4, 256, 0, stream>>>(Yb, hln, XIN, nullptr);
    vloc_kernel<<<NR/4, 256, 0, stream>>>(XIN, hw2, hb2, out_v);
}